// Round 3
// baseline (259.899 us; speedup 1.0000x reference)
//
#include <hip/hip_runtime.h>

// Problem constants (match the reference)
constexpr int T   = 4096;
constexpr int N   = 16;
constexpr int C   = 512;
constexpr int NC  = N * C;        // 8192 columns
constexpr int NC4 = NC / 4;       // 2048 float4 columns
constexpr int CH  = 128;          // number of T-chunks
constexpr int L   = T / CH;       // 32 steps per chunk
constexpr int TNC = T * NC;

// ---------------------------------------------------------------------------
// Pass 1: per-chunk column sums. grid = CH*NC4/256 = 1024 blocks x 256 thr.
// Each thread owns one float4 column slice of one chunk: 32 coalesced,
// fully independent 16B loads (deep MLP), 4 running sums.
// ---------------------------------------------------------------------------
__global__ __launch_bounds__(256) void chunk_sums(
    const float* __restrict__ x, float* __restrict__ partial)
{
    int gid  = blockIdx.x * blockDim.x + threadIdx.x;   // 0 .. CH*NC4-1
    int ch   = gid >> 11;          // / NC4 (2048)
    int col4 = gid & (NC4 - 1);

    const float4* xp = reinterpret_cast<const float4*>(x);
    float4 s = make_float4(0.f, 0.f, 0.f, 0.f);
    int base = ch * L * NC4 + col4;
#pragma unroll 8
    for (int i = 0; i < L; ++i) {
        float4 v = xp[base + i * NC4];
        s.x += v.x; s.y += v.y; s.z += v.z; s.w += v.w;
    }
    reinterpret_cast<float4*>(partial)[ch * NC4 + col4] = s;
}

// ---------------------------------------------------------------------------
// Pass 2: exclusive scan over the CH chunk-sums per column, IN PLACE, batched
// by 16 so the loads of each batch are independent (no serialized global
// round-trips; in-place is safe because each batch reads before it writes the
// same addresses). x-only prefix (base added in pass 3). Also emits
// new_cached_len — note the harness reads the WHOLE d_out as float32 and
// splits it, so the int output must be stored as float VALUES.
// grid = NC/256 = 32 blocks; 8 MB touched -> few us.
// ---------------------------------------------------------------------------
__global__ __launch_bounds__(256) void scan_chunks(
    float* __restrict__ partial,
    const int* __restrict__ cached_len,
    float* __restrict__ out_len)
{
    int nc = blockIdx.x * blockDim.x + threadIdx.x;  // 0..NC-1
    float running = 0.f;
#pragma unroll
    for (int ch0 = 0; ch0 < CH; ch0 += 16) {
        float v[16];
#pragma unroll
        for (int i = 0; i < 16; ++i) v[i] = partial[(ch0 + i) * NC + nc];
#pragma unroll
        for (int i = 0; i < 16; ++i) {
            partial[(ch0 + i) * NC + nc] = running;   // exclusive prefix of x
            running += v[i];
        }
    }
    if (nc < N) out_len[nc] = (float)(cached_len[nc] + T);
}

// ---------------------------------------------------------------------------
// Pass 3: local cumsum + prefix, add cached base, divide by counts, store.
// Same decomposition as pass 1. Last chunk also writes new_cached_avg.
// ---------------------------------------------------------------------------
__global__ __launch_bounds__(256) void finalize(
    const float* __restrict__ x,
    const float* __restrict__ partial,
    const int* __restrict__ cached_len,
    const float* __restrict__ cached_avg,
    float* __restrict__ out,
    float* __restrict__ out_avg)
{
    int gid  = blockIdx.x * blockDim.x + threadIdx.x;
    int ch   = gid >> 11;
    int col4 = gid & (NC4 - 1);
    int n    = col4 >> 7;          // (col4*4)/512
    float lenf = (float)cached_len[n];

    // base = cached_avg * len (added last, matching reference association)
    float4 b = reinterpret_cast<const float4*>(cached_avg)[col4];
    b.x *= lenf; b.y *= lenf; b.z *= lenf; b.w *= lenf;

    const float4* xp = reinterpret_cast<const float4*>(x);
    float4 s = reinterpret_cast<const float4*>(partial)[ch * NC4 + col4];
    float4* op = reinterpret_cast<float4*>(out);

    int t0 = ch * L;
    float4 o = make_float4(0.f, 0.f, 0.f, 0.f);
#pragma unroll 8
    for (int i = 0; i < L; ++i) {
        int t = t0 + i;
        float4 v = xp[t * NC4 + col4];
        s.x += v.x; s.y += v.y; s.z += v.z; s.w += v.w;
        // match reference rounding: exact fp32 divide, then multiply
        float r = 1.0f / ((float)(t + 1) + lenf);
        o.x = (s.x + b.x) * r;
        o.y = (s.y + b.y) * r;
        o.z = (s.z + b.z) * r;
        o.w = (s.w + b.w) * r;
        op[t * NC4 + col4] = o;
    }
    if (ch == CH - 1) {
        reinterpret_cast<float4*>(out_avg)[col4] = o;   // new_x[-1]
    }
}

// ---------------------------------------------------------------------------
extern "C" void kernel_launch(void* const* d_in, const int* in_sizes, int n_in,
                              void* d_out, int out_size, void* d_ws, size_t ws_size,
                              hipStream_t stream)
{
    const float* x          = (const float*)d_in[0];
    const int*   cached_len = (const int*)d_in[1];
    const float* cached_avg = (const float*)d_in[2];

    // d_out (ALL float32): new_x (T*N*C) | new_cached_len (N, as float values)
    //                      | new_cached_avg (N*C)
    float* out     = (float*)d_out;
    float* out_len = out + TNC;
    float* out_avg = out + TNC + N;

    float* partial = (float*)d_ws;   // CH*NC floats = 4 MB

    chunk_sums <<<CH * NC4 / 256, 256, 0, stream>>>(x, partial);
    scan_chunks<<<NC / 256,       256, 0, stream>>>(partial, cached_len, out_len);
    finalize   <<<CH * NC4 / 256, 256, 0, stream>>>(x, partial, cached_len, cached_avg,
                                                    out, out_avg);
}